// Round 3
// baseline (368.130 us; speedup 1.0000x reference)
//
#include <hip/hip_runtime.h>
#include <hip/hip_bf16.h>
#include <stdint.h>

#define B_ROWS 131072
#define DDIM 256
#define GATE_BLOCKS 2048          // B_ROWS / 64
#define PREPACK_BLOCKS 56         // 7 matrices x 8 s-slabs
#define TILES_PER_EXPERT 1024     // 128 rows per tile, over-provisioned per expert

typedef short bf16x8 __attribute__((ext_vector_type(8)));
typedef float f32x4 __attribute__((ext_vector_type(4)));

__device__ __forceinline__ unsigned short f32_to_bf16_rne(float f) {
    union { float f; uint32_t u; } v; v.f = f;
    uint32_t u = v.u;
    u += 0x7fffu + ((u >> 16) & 1u);
    return (unsigned short)(u >> 16);
}

// ---------------------------------------------------------------------------
// Fused kernel A: blocks [0,2048) = gate (fp64-exact argmax + bucketing),
// blocks [2048,2104) = weight prepack into MFMA B-frag order (bf16).
// B-frag layout: packed[s][t][lane][j] = W[32s + 8*(lane>>4) + j][16t + (lane&15)]
// ---------------------------------------------------------------------------
__global__ __launch_bounds__(256) void gate_prepack_kernel(
    const float* __restrict__ x, const float* __restrict__ Wg,
    const float* __restrict__ bg, const float* __restrict__ Wl,
    const float* __restrict__ Wm, const float* __restrict__ Wr,
    int* __restrict__ counts, int* __restrict__ perm,
    unsigned short* __restrict__ wpack)
{
    __shared__ float smemf[4160];          // 16640 B, shared by both roles
    int t = threadIdx.x;

    if (blockIdx.x >= GATE_BLOCKS) {
        // ----- prepack: one (matrix m, s-slab) per block -----
        int bid = blockIdx.x - GATE_BLOCKS;
        int m = bid >> 3, s = bid & 7;
        const float* src = (m < 4) ? (Wl + m * 65536)
                         : (m < 6) ? (Wm + (m - 4) * 65536)
                                   : Wr;
        unsigned short* lds = (unsigned short*)smemf;   // 8192 ushorts = 1024 uint4
        #pragma unroll
        for (int i = 0; i < 8; i++) {
            int v = i * 256 + t;            // float4 id within 32x256 slab
            int kp = v >> 6;                // 0..31 (k - 32s)
            int n0 = (v & 63) * 4;
            float4 w = *(const float4*)(src + (32 * s + kp) * 256 + n0);
            #pragma unroll
            for (int c = 0; c < 4; c++) {
                int n = n0 + c;
                float val = (c == 0) ? w.x : (c == 1) ? w.y : (c == 2) ? w.z : w.w;
                int o = (n >> 4) * 512 + ((n & 15) + 16 * (kp >> 3)) * 8 + (kp & 7);
                lds[o] = f32_to_bf16_rne(val);
            }
        }
        __syncthreads();
        uint4* outv = (uint4*)(wpack + (m * 8 + s) * 8192);
        const uint4* ldsv = (const uint4*)lds;
        #pragma unroll
        for (int q = 0; q < 4; q++)                 // ALL 1024 uint4 (r2 bug: only 512)
            outv[q * 256 + t] = ldsv[q * 256 + t];
        return;
    }

    // ----- gate: 64 rows per block, 4 threads per row -----
    float* wgl = smemf;                    // Wg[k][e] flat, 1024 floats
    int* hcount = (int*)(smemf + 1024);
    int* hbase  = (int*)(smemf + 1028);

    ((float4*)wgl)[t] = ((const float4*)Wg)[t];
    if (t < 4) hcount[t] = 0;
    __syncthreads();

    int lrow = t >> 2, sub = t & 3;
    int row = blockIdx.x * 64 + lrow;
    const float* xr = x + (long)row * DDIM;

    double a0 = 0.0, a1 = 0.0, a2 = 0.0, a3 = 0.0;
    #pragma unroll
    for (int i = 0; i < 16; i++) {
        int k0 = i * 16 + sub * 4;
        float4 v = *(const float4*)(xr + k0);
        #pragma unroll
        for (int kk = 0; kk < 4; kk++) {
            float xv = (kk == 0) ? v.x : (kk == 1) ? v.y : (kk == 2) ? v.z : v.w;
            float4 w = *(const float4*)(wgl + (k0 + kk) * 4);   // ds_read_b128
            a0 += (double)xv * (double)w.x;
            a1 += (double)xv * (double)w.y;
            a2 += (double)xv * (double)w.z;
            a3 += (double)xv * (double)w.w;
        }
    }
    a0 += __shfl_xor(a0, 1); a0 += __shfl_xor(a0, 2);
    a1 += __shfl_xor(a1, 1); a1 += __shfl_xor(a1, 2);
    a2 += __shfl_xor(a2, 1); a2 += __shfl_xor(a2, 2);
    a3 += __shfl_xor(a3, 1); a3 += __shfl_xor(a3, 2);

    int myidx = 0, mylpos = 0;
    if (sub == 0) {
        double l0 = a0 + (double)bg[0];
        double l1 = a1 + (double)bg[1];
        double l2 = a2 + (double)bg[2];
        double l3 = a3 + (double)bg[3];
        double best = l0; myidx = 0;
        if (l1 > best) { best = l1; myidx = 1; }   // strict > = first-max tiebreak
        if (l2 > best) { best = l2; myidx = 2; }
        if (l3 > best) { best = l3; myidx = 3; }
        mylpos = atomicAdd(&hcount[myidx], 1);
    }
    __syncthreads();
    if (t < 4) hbase[t] = atomicAdd(&counts[t], hcount[t]);
    __syncthreads();
    if (sub == 0) perm[myidx * B_ROWS + hbase[myidx] + mylpos] = row;
}

// ---------------------------------------------------------------------------
// Kernel B: fused 3-layer MLP. Block = 128 rows, 256 thr (4 waves).
// Wave wv owns 64 output cols (n-tiles 4wv..4wv+3) and ALL 8 m-tiles ->
// each B-fragment load is reused 8x (wpack L2 traffic /8 vs round 1).
// apack layout [s:8][mt:8][lane:64][j:8] bf16 = 64 KB, conflict-free b128.
// ---------------------------------------------------------------------------
__global__ __launch_bounds__(256, 2) void mlp_kernel(
    const float* __restrict__ x, const unsigned short* __restrict__ wpack,
    const float* __restrict__ b_leaf, const float* __restrict__ b_mid,
    const float* __restrict__ b_root, const int* __restrict__ counts,
    const int* __restrict__ perm, float* __restrict__ out)
{
    __shared__ unsigned short apack[32768];   // 64 KB
    __shared__ int rowsLds[128];

    int e = blockIdx.x >> 10;                 // expert 0..3
    int tile = blockIdx.x & 1023;
    int cnt = counts[e];
    int base = tile * 128;
    if (base >= cnt) return;

    int t = threadIdx.x;
    if (t < 128) {
        int src = base + t;
        if (src >= cnt) src = base;           // dup a valid row for padding
        rowsLds[t] = perm[e * B_ROWS + src];
    }
    __syncthreads();

    // gather X -> LDS packed A-frags (2 threads per row)
    {
        int r = t >> 1, sub = t & 1;
        const float* xr = x + (long)rowsLds[r] * DDIM;
        int mt = r >> 4, rl = r & 15;
        #pragma unroll
        for (int i = 0; i < 32; i++) {
            int k0 = sub * 128 + i * 4;
            float4 v = *(const float4*)(xr + k0);
            int s = k0 >> 5;
            int fl = rl + 16 * ((k0 >> 3) & 3);
            ushort4 u;
            u.x = f32_to_bf16_rne(v.x);
            u.y = f32_to_bf16_rne(v.y);
            u.z = f32_to_bf16_rne(v.z);
            u.w = f32_to_bf16_rne(v.w);
            *(ushort4*)&apack[((s * 8 + mt) * 64 + fl) * 8 + (k0 & 7)] = u;
        }
    }
    __syncthreads();

    int wv = t >> 6, l = t & 63;
    f32x4 acc[8][4];
    float bias[4];

    auto run_level = [&](const unsigned short* wp, const float* bias_g) {
        #pragma unroll
        for (int nt = 0; nt < 4; nt++)
            bias[nt] = bias_g[(4 * wv + nt) * 16 + (l & 15)];
        f32x4 z = {0.f, 0.f, 0.f, 0.f};
        #pragma unroll
        for (int mt = 0; mt < 8; mt++)
            #pragma unroll
            for (int nt = 0; nt < 4; nt++) acc[mt][nt] = z;

        const bf16x8* wpv = (const bf16x8*)wp;
        #pragma unroll
        for (int s = 0; s < 8; s++) {
            bf16x8 b[4];
            #pragma unroll
            for (int nt = 0; nt < 4; nt++)
                b[nt] = wpv[(s * 16 + 4 * wv + nt) * 64 + l];
            const bf16x8* ap = (const bf16x8*)(apack + s * 8 * 64 * 8);
            #pragma unroll
            for (int mt = 0; mt < 8; mt++) {
                bf16x8 a = ap[mt * 64 + l];
                #pragma unroll
                for (int nt = 0; nt < 4; nt++)
                    acc[mt][nt] = __builtin_amdgcn_mfma_f32_16x16x32_bf16(
                        a, b[nt], acc[mt][nt], 0, 0, 0);
            }
        }
    };

    auto epilogue_lds = [&]() {
        #pragma unroll
        for (int nt = 0; nt < 4; nt++) {
            int col = (4 * wv + nt) * 16 + (l & 15);
            int s = col >> 5;
            int fq = (col >> 3) & 3;
            int j = col & 7;
            #pragma unroll
            for (int mt = 0; mt < 8; mt++) {
                #pragma unroll
                for (int r = 0; r < 4; r++) {
                    float v = fmaxf(acc[mt][nt][r] + bias[nt], 0.f);
                    int fl = ((l >> 4) << 2) + r + 16 * fq;
                    apack[((s * 8 + mt) * 64 + fl) * 8 + j] = f32_to_bf16_rne(v);
                }
            }
        }
    };

    // level 1: leaf expert e
    run_level(wpack + e * 65536, b_leaf + e * 256);
    __syncthreads();
    epilogue_lds();
    __syncthreads();

    // level 2: mid expert e>>1
    run_level(wpack + (4 + (e >> 1)) * 65536, b_mid + (e >> 1) * 256);
    __syncthreads();
    epilogue_lds();
    __syncthreads();

    // level 3: root, scatter-store
    run_level(wpack + 6 * 65536, b_root);
    #pragma unroll
    for (int nt = 0; nt < 4; nt++) {
        int col = (4 * wv + nt) * 16 + (l & 15);
        #pragma unroll
        for (int mt = 0; mt < 8; mt++) {
            #pragma unroll
            for (int r = 0; r < 4; r++) {
                int row_local = mt * 16 + ((l >> 4) << 2) + r;
                if (base + row_local < cnt) {
                    long grow = rowsLds[row_local];
                    out[grow * DDIM + col] = fmaxf(acc[mt][nt][r] + bias[nt], 0.f);
                }
            }
        }
    }
}

extern "C" void kernel_launch(void* const* d_in, const int* in_sizes, int n_in,
                              void* d_out, int out_size, void* d_ws, size_t ws_size,
                              hipStream_t stream) {
    const float* x      = (const float*)d_in[0];
    const float* Wg     = (const float*)d_in[1];
    const float* bg     = (const float*)d_in[2];
    const float* W_leaf = (const float*)d_in[3];
    const float* b_leaf = (const float*)d_in[4];
    const float* W_mid  = (const float*)d_in[5];
    const float* b_mid  = (const float*)d_in[6];
    const float* W_root = (const float*)d_in[7];
    const float* b_root = (const float*)d_in[8];
    float* out = (float*)d_out;

    char* ws = (char*)d_ws;
    int* counts = (int*)ws;                                    // 16 B
    int* perm = (int*)(ws + 256);                              // 2 MB
    unsigned short* wpack = (unsigned short*)(ws + (4 << 20)); // 896 KB

    hipMemsetAsync(counts, 0, 16, stream);
    gate_prepack_kernel<<<GATE_BLOCKS + PREPACK_BLOCKS, 256, 0, stream>>>(
        x, Wg, bg, W_leaf, W_mid, W_root, counts, perm, wpack);
    mlp_kernel<<<4 * TILES_PER_EXPERT, 256, 0, stream>>>(
        x, wpack, b_leaf, b_mid, b_root, counts, perm, out);
}

// Round 4
// 333.461 us; speedup vs baseline: 1.1040x; 1.1040x over previous
//
#include <hip/hip_runtime.h>
#include <hip/hip_bf16.h>
#include <stdint.h>

#define B_ROWS 131072
#define DDIM 256
#define GATE_BLOCKS 2048          // B_ROWS / 64
#define PREPACK_BLOCKS 56         // 7 matrices x 8 s-slabs
#define TILES_PER_EXPERT 2048     // 64 rows per tile, over-provisioned per expert

typedef short bf16x8 __attribute__((ext_vector_type(8)));
typedef float f32x4 __attribute__((ext_vector_type(4)));

__device__ __forceinline__ unsigned short f32_to_bf16_rne(float f) {
    union { float f; uint32_t u; } v; v.f = f;
    uint32_t u = v.u;
    u += 0x7fffu + ((u >> 16) & 1u);
    return (unsigned short)(u >> 16);
}

// ---------------------------------------------------------------------------
// Fused kernel A (unchanged from round 3, passing): blocks [0,2048) = gate,
// blocks [2048,2104) = weight prepack into MFMA B-frag order (bf16).
// B-frag layout: packed[s][t][lane][j] = W[32s + 8*(lane>>4) + j][16t + (lane&15)]
// ---------------------------------------------------------------------------
__global__ __launch_bounds__(256) void gate_prepack_kernel(
    const float* __restrict__ x, const float* __restrict__ Wg,
    const float* __restrict__ bg, const float* __restrict__ Wl,
    const float* __restrict__ Wm, const float* __restrict__ Wr,
    int* __restrict__ counts, int* __restrict__ perm,
    unsigned short* __restrict__ wpack)
{
    __shared__ float smemf[4160];          // 16640 B, shared by both roles
    int t = threadIdx.x;

    if (blockIdx.x >= GATE_BLOCKS) {
        // ----- prepack: one (matrix m, s-slab) per block -----
        int bid = blockIdx.x - GATE_BLOCKS;
        int m = bid >> 3, s = bid & 7;
        const float* src = (m < 4) ? (Wl + m * 65536)
                         : (m < 6) ? (Wm + (m - 4) * 65536)
                                   : Wr;
        unsigned short* lds = (unsigned short*)smemf;   // 8192 ushorts = 1024 uint4
        #pragma unroll
        for (int i = 0; i < 8; i++) {
            int v = i * 256 + t;            // float4 id within 32x256 slab
            int kp = v >> 6;                // 0..31 (k - 32s)
            int n0 = (v & 63) * 4;
            float4 w = *(const float4*)(src + (32 * s + kp) * 256 + n0);
            #pragma unroll
            for (int c = 0; c < 4; c++) {
                int n = n0 + c;
                float val = (c == 0) ? w.x : (c == 1) ? w.y : (c == 2) ? w.z : w.w;
                int o = (n >> 4) * 512 + ((n & 15) + 16 * (kp >> 3)) * 8 + (kp & 7);
                lds[o] = f32_to_bf16_rne(val);
            }
        }
        __syncthreads();
        uint4* outv = (uint4*)(wpack + (m * 8 + s) * 8192);
        const uint4* ldsv = (const uint4*)lds;
        #pragma unroll
        for (int q = 0; q < 4; q++)
            outv[q * 256 + t] = ldsv[q * 256 + t];
        return;
    }

    // ----- gate: 64 rows per block, 4 threads per row (fp64-exact argmax) -----
    float* wgl = smemf;                    // Wg[k][e] flat, 1024 floats
    int* hcount = (int*)(smemf + 1024);
    int* hbase  = (int*)(smemf + 1028);

    ((float4*)wgl)[t] = ((const float4*)Wg)[t];
    if (t < 4) hcount[t] = 0;
    __syncthreads();

    int lrow = t >> 2, sub = t & 3;
    int row = blockIdx.x * 64 + lrow;
    const float* xr = x + (long)row * DDIM;

    double a0 = 0.0, a1 = 0.0, a2 = 0.0, a3 = 0.0;
    #pragma unroll
    for (int i = 0; i < 16; i++) {
        int k0 = i * 16 + sub * 4;
        float4 v = *(const float4*)(xr + k0);
        #pragma unroll
        for (int kk = 0; kk < 4; kk++) {
            float xv = (kk == 0) ? v.x : (kk == 1) ? v.y : (kk == 2) ? v.z : v.w;
            float4 w = *(const float4*)(wgl + (k0 + kk) * 4);   // ds_read_b128
            a0 += (double)xv * (double)w.x;
            a1 += (double)xv * (double)w.y;
            a2 += (double)xv * (double)w.z;
            a3 += (double)xv * (double)w.w;
        }
    }
    a0 += __shfl_xor(a0, 1); a0 += __shfl_xor(a0, 2);
    a1 += __shfl_xor(a1, 1); a1 += __shfl_xor(a1, 2);
    a2 += __shfl_xor(a2, 1); a2 += __shfl_xor(a2, 2);
    a3 += __shfl_xor(a3, 1); a3 += __shfl_xor(a3, 2);

    int myidx = 0, mylpos = 0;
    if (sub == 0) {
        double l0 = a0 + (double)bg[0];
        double l1 = a1 + (double)bg[1];
        double l2 = a2 + (double)bg[2];
        double l3 = a3 + (double)bg[3];
        double best = l0; myidx = 0;
        if (l1 > best) { best = l1; myidx = 1; }   // strict > = first-max tiebreak
        if (l2 > best) { best = l2; myidx = 2; }
        if (l3 > best) { best = l3; myidx = 3; }
        mylpos = atomicAdd(&hcount[myidx], 1);
    }
    __syncthreads();
    if (t < 4) hbase[t] = atomicAdd(&counts[t], hcount[t]);
    __syncthreads();
    if (sub == 0) perm[myidx * B_ROWS + hbase[myidx] + mylpos] = row;
}

// ---------------------------------------------------------------------------
// Kernel B: fused 3-layer MLP. Block = 64 rows, 512 thr (8 waves).
// Wave wv owns n-tiles {2wv, 2wv+1} (32 cols) x all 4 m-tiles -> acc = 32
// regs/lane (vs 64 in R1) -> ~82 total regs -> 6 waves/SIMD, 24 waves/CU
// (2x R1's effective concurrency). LDS 32.5 KB.
// apack layout [s:8][mt:4][lane:64][j:8] bf16, conflict-free ds_read_b128.
// ---------------------------------------------------------------------------
__global__ __launch_bounds__(512, 6) void mlp_kernel(
    const float* __restrict__ x, const unsigned short* __restrict__ wpack,
    const float* __restrict__ b_leaf, const float* __restrict__ b_mid,
    const float* __restrict__ b_root, const int* __restrict__ counts,
    const int* __restrict__ perm, float* __restrict__ out)
{
    __shared__ unsigned short apack[16384];   // 32 KB
    __shared__ int rowsLds[64];

    int e = blockIdx.x >> 11;                 // expert 0..3
    int tile = blockIdx.x & 2047;
    int cnt = counts[e];
    int base = tile * 64;
    if (base >= cnt) return;

    int t = threadIdx.x;
    if (t < 64) {
        int src = base + t;
        rowsLds[t] = perm[e * B_ROWS + (src < cnt ? src : base)];
    }
    __syncthreads();

    // gather X -> LDS packed A-frags (8 threads per row)
    {
        int r = t >> 3, sub = t & 7;
        const float* xr = x + (long)rowsLds[r] * DDIM;
        int mt = r >> 4, rl = r & 15;
        #pragma unroll
        for (int i = 0; i < 8; i++) {
            int k0 = i * 32 + sub * 4;
            float4 v = *(const float4*)(xr + k0);
            int s = k0 >> 5;                   // = i
            int fl = rl + 16 * ((k0 >> 3) & 3);
            ushort4 u;
            u.x = f32_to_bf16_rne(v.x);
            u.y = f32_to_bf16_rne(v.y);
            u.z = f32_to_bf16_rne(v.z);
            u.w = f32_to_bf16_rne(v.w);
            *(ushort4*)&apack[((s * 4 + mt) * 64 + fl) * 8 + (k0 & 7)] = u;
        }
    }
    __syncthreads();

    int wv = t >> 6, l = t & 63;
    f32x4 acc[4][2];
    float bias[2];

    auto run_level = [&](const unsigned short* wp, const float* bias_g) {
        #pragma unroll
        for (int nt = 0; nt < 2; nt++)
            bias[nt] = bias_g[(2 * wv + nt) * 16 + (l & 15)];
        f32x4 z = {0.f, 0.f, 0.f, 0.f};
        #pragma unroll
        for (int mt = 0; mt < 4; mt++)
            #pragma unroll
            for (int nt = 0; nt < 2; nt++) acc[mt][nt] = z;

        const bf16x8* wpv = (const bf16x8*)wp;
        #pragma unroll
        for (int s = 0; s < 8; s++) {
            bf16x8 b[2];
            #pragma unroll
            for (int nt = 0; nt < 2; nt++)
                b[nt] = wpv[(s * 16 + 2 * wv + nt) * 64 + l];
            const bf16x8* ap = (const bf16x8*)(apack + s * 4 * 64 * 8);
            #pragma unroll
            for (int mt = 0; mt < 4; mt++) {
                bf16x8 a = ap[mt * 64 + l];
                #pragma unroll
                for (int nt = 0; nt < 2; nt++)
                    acc[mt][nt] = __builtin_amdgcn_mfma_f32_16x16x32_bf16(
                        a, b[nt], acc[mt][nt], 0, 0, 0);
            }
        }
    };

    auto epilogue_lds = [&]() {
        #pragma unroll
        for (int nt = 0; nt < 2; nt++) {
            int col = (2 * wv + nt) * 16 + (l & 15);
            int s = col >> 5;
            int fq = (col >> 3) & 3;
            int j = col & 7;
            #pragma unroll
            for (int mt = 0; mt < 4; mt++) {
                #pragma unroll
                for (int r = 0; r < 4; r++) {
                    float v = fmaxf(acc[mt][nt][r] + bias[nt], 0.f);
                    int fl = ((l >> 4) << 2) + r + 16 * fq;
                    apack[((s * 4 + mt) * 64 + fl) * 8 + j] = f32_to_bf16_rne(v);
                }
            }
        }
    };

    // level 1: leaf expert e
    run_level(wpack + e * 65536, b_leaf + e * 256);
    __syncthreads();
    epilogue_lds();
    __syncthreads();

    // level 2: mid expert e>>1
    run_level(wpack + (4 + (e >> 1)) * 65536, b_mid + (e >> 1) * 256);
    __syncthreads();
    epilogue_lds();
    __syncthreads();

    // level 3: root, scatter-store
    run_level(wpack + 6 * 65536, b_root);
    #pragma unroll
    for (int nt = 0; nt < 2; nt++) {
        int col = (2 * wv + nt) * 16 + (l & 15);
        #pragma unroll
        for (int mt = 0; mt < 4; mt++) {
            #pragma unroll
            for (int r = 0; r < 4; r++) {
                int row_local = mt * 16 + ((l >> 4) << 2) + r;
                if (base + row_local < cnt) {
                    long grow = rowsLds[row_local];
                    out[grow * DDIM + col] = fmaxf(acc[mt][nt][r] + bias[nt], 0.f);
                }
            }
        }
    }
}

extern "C" void kernel_launch(void* const* d_in, const int* in_sizes, int n_in,
                              void* d_out, int out_size, void* d_ws, size_t ws_size,
                              hipStream_t stream) {
    const float* x      = (const float*)d_in[0];
    const float* Wg     = (const float*)d_in[1];
    const float* bg     = (const float*)d_in[2];
    const float* W_leaf = (const float*)d_in[3];
    const float* b_leaf = (const float*)d_in[4];
    const float* W_mid  = (const float*)d_in[5];
    const float* b_mid  = (const float*)d_in[6];
    const float* W_root = (const float*)d_in[7];
    const float* b_root = (const float*)d_in[8];
    float* out = (float*)d_out;

    char* ws = (char*)d_ws;
    int* counts = (int*)ws;                                    // 16 B
    int* perm = (int*)(ws + 256);                              // 2 MB
    unsigned short* wpack = (unsigned short*)(ws + (4 << 20)); // 896 KB

    hipMemsetAsync(counts, 0, 16, stream);
    gate_prepack_kernel<<<GATE_BLOCKS + PREPACK_BLOCKS, 256, 0, stream>>>(
        x, Wg, bg, W_leaf, W_mid, W_root, counts, perm, wpack);
    mlp_kernel<<<4 * TILES_PER_EXPERT, 512, 0, stream>>>(
        x, wpack, b_leaf, b_mid, b_root, counts, perm, out);
}